// Round 3
// baseline (103.469 us; speedup 1.0000x reference)
//
#include <hip/hip_runtime.h>
#include <hip/hip_bf16.h>
#include <float.h>

typedef __attribute__((ext_vector_type(8))) short short8;
typedef __attribute__((ext_vector_type(4))) float f32x4;
typedef unsigned short ushort_t;

#define N_E   1024
#define E_DIM 256
#define N_TOKS 65536

// round-to-nearest-even fp32 -> bf16
__device__ inline ushort_t f2bf(float f) {
  unsigned int u = __float_as_uint(f);
  unsigned int r = u + 0x7FFFu + ((u >> 16) & 1u);
  return (ushort_t)(r >> 16);
}

// ---------------------------------------------------------------------------
// Prep: emb fp32 -> bf16 in MFMA-B-fragment order + enorm = sum(e^2)
// byte = (code/16)*8192 + (k/8)*256 + (code%16)*16 + (k%8)*2
// ---------------------------------------------------------------------------
__global__ __launch_bounds__(256) void vq_prep(const float* __restrict__ emb,
                                               ushort_t* __restrict__ embT,
                                               float* __restrict__ enorm) {
  const int code = blockIdx.x;     // 0..1023
  const int t    = threadIdx.x;    // 0..255 = k
  float v = emb[(size_t)code * E_DIM + t];
  embT[(size_t)(code >> 4) * 4096 + (t >> 3) * 128 + (code & 15) * 8 + (t & 7)] = f2bf(v);
  float sq = v * v;
  #pragma unroll
  for (int m = 1; m < 64; m <<= 1) sq += __shfl_xor(sq, m);
  __shared__ float ws3[4];
  if ((t & 63) == 0) ws3[t >> 6] = sq;
  __syncthreads();
  if (t == 0) enorm[code] = ws3[0] + ws3[1] + ws3[2] + ws3[3];
}

// ---------------------------------------------------------------------------
// Main: grid = 512 token-tiles x 2 code-halves (1024 blocks -> 4/CU).
// Block: 128 tokens, 4 waves, scans 512 codes = 32 tiles of 16 codes (8 KB),
// triple-buffered, counted vmcnt(2) + raw s_barrier (prefetch stays in
// flight across barriers). Emits per-token partial (s_best, idx) + znorm.
// ---------------------------------------------------------------------------
__global__ __launch_bounds__(256, 4) void vq_main(
    const float* __restrict__ z, const ushort_t* __restrict__ embT,
    const float* __restrict__ enorm,
    float* __restrict__ s_part, int* __restrict__ i_part,
    float* __restrict__ znorm_out) {
  __shared__ ushort_t ldsB[3][4096];   // 3 x 8 KB
  __shared__ float enorm_lds[512];     // this half's enorm

  const int tid  = threadIdx.x;
  const int lane = tid & 63;
  const int wv   = tid >> 6;
  const int bid  = blockIdx.x;
  const int half = bid & 1;
  const int tt   = bid >> 1;
  const int lrow = lane & 15;   // A: token row; B/D: code col
  const int lk   = lane >> 4;   // k-group / D row-group
  const int tileBase = half * 32;      // global 8KB-tile index base

  const char* gbase = (const char*)embT;
  // tile = 16 codes x 256 k = 8 KB; each wave stages its 2 KB quarter
#define STAGE(BUF, TILE) do {                                                  \
    const char* g = gbase + (size_t)(TILE) * 8192 + wv * 2048 + lane * 16;     \
    char* lp = ((char*)&ldsB[(BUF)][0]) + wv * 2048;                           \
    __builtin_amdgcn_global_load_lds(                                          \
        (const __attribute__((address_space(1))) void*)g,                      \
        (__attribute__((address_space(3))) void*)lp, 16, 0, 0);                \
    __builtin_amdgcn_global_load_lds(                                          \
        (const __attribute__((address_space(1))) void*)(g + 1024),             \
        (__attribute__((address_space(3))) void*)(lp + 1024), 16, 0, 0);       \
  } while (0)

  // prefetch tiles 0,1 — latency hides under the z load phase below
  STAGE(0, tileBase + 0);
  STAGE(1, tileBase + 1);

  // ---- A fragments (z -> bf16) + fp32 znorm --------------------------------
  short8 afr[2][8];
  #pragma unroll
  for (int h = 0; h < 2; ++h) {
    const float* zp = z + (size_t)(tt * 128 + wv * 32 + h * 16 + lrow) * E_DIM + lk * 8;
    float zn = 0.f;
    #pragma unroll
    for (int kk = 0; kk < 8; ++kk) {
      float4 v0 = *(const float4*)(zp + kk * 32);
      float4 v1 = *(const float4*)(zp + kk * 32 + 4);
      zn += v0.x * v0.x + v0.y * v0.y + v0.z * v0.z + v0.w * v0.w;
      zn += v1.x * v1.x + v1.y * v1.y + v1.z * v1.z + v1.w * v1.w;
      short8 a;
      a[0] = (short)f2bf(v0.x); a[1] = (short)f2bf(v0.y);
      a[2] = (short)f2bf(v0.z); a[3] = (short)f2bf(v0.w);
      a[4] = (short)f2bf(v1.x); a[5] = (short)f2bf(v1.y);
      a[6] = (short)f2bf(v1.z); a[7] = (short)f2bf(v1.w);
      afr[h][kk] = a;
    }
    zn += __shfl_xor(zn, 16);
    zn += __shfl_xor(zn, 32);
    if (half == 0 && lane < 16)
      znorm_out[tt * 128 + wv * 32 + h * 16 + lane] = zn;
  }

  // this half's enorm -> LDS (512 floats)
  ((float2*)enorm_lds)[tid] = ((const float2*)(enorm + half * 512))[tid];

  __syncthreads();   // drains prologue DMA too; tiles 0,1 ready

  float bs[2][4];
  int   bi[2][4];
  #pragma unroll
  for (int r = 0; r < 4; ++r) {
    bs[0][r] = FLT_MAX; bs[1][r] = FLT_MAX; bi[0][r] = 0; bi[1][r] = 0;
  }

  int cb = 0;           // compute buffer
  int sb = 2;           // stage buffer
  for (int t = 0; t < 32; ++t) {
    if (t < 30) STAGE(sb, tileBase + t + 2);
    const char* tb = (const char*)&ldsB[cb][0] + lk * 256 + lrow * 16;
    f32x4 acc0 = {0.f, 0.f, 0.f, 0.f};
    f32x4 acc1 = {0.f, 0.f, 0.f, 0.f};
    #pragma unroll
    for (int kk = 0; kk < 8; ++kk) {
      short8 bfr = *(const short8*)(tb + kk * 1024);
      acc0 = __builtin_amdgcn_mfma_f32_16x16x32_bf16(afr[0][kk], bfr, acc0, 0, 0, 0);
      acc1 = __builtin_amdgcn_mfma_f32_16x16x32_bf16(afr[1][kk], bfr, acc1, 0, 0, 0);
    }
    const float en = enorm_lds[t * 16 + lrow];
    const int code = half * 512 + t * 16 + lrow;
    #pragma unroll
    for (int r = 0; r < 4; ++r) {
      float s0 = fmaf(-2.f, acc0[r], en);
      if (s0 < bs[0][r]) { bs[0][r] = s0; bi[0][r] = code; }
      float s1 = fmaf(-2.f, acc1[r], en);
      if (s1 < bs[1][r]) { bs[1][r] = s1; bi[1][r] = code; }
    }
    // keep next tile's DMA in flight; ensure tile t+1 landed
    if (t < 30)       asm volatile("s_waitcnt vmcnt(2)" ::: "memory");
    else if (t == 30) asm volatile("s_waitcnt vmcnt(0)" ::: "memory");
    if (t < 31) __builtin_amdgcn_s_barrier();
    cb = cb + 1; if (cb >= 3) cb = 0;
    sb = sb + 1; if (sb >= 3) sb = 0;
  }
#undef STAGE

  // ---- cross-lane argmin reduce over the 16 code columns -------------------
  #pragma unroll
  for (int m = 1; m < 16; m <<= 1) {
    #pragma unroll
    for (int h = 0; h < 2; ++h) {
      #pragma unroll
      for (int r = 0; r < 4; ++r) {
        float s2 = __shfl_xor(bs[h][r], m);
        int   i2 = __shfl_xor(bi[h][r], m);
        if (s2 < bs[h][r] || (s2 == bs[h][r] && i2 < bi[h][r])) {
          bs[h][r] = s2; bi[h][r] = i2;
        }
      }
    }
  }
  if (lrow == 0) {
    const size_t pb = (size_t)half * N_TOKS + tt * 128;
    #pragma unroll
    for (int h = 0; h < 2; ++h) {
      #pragma unroll
      for (int r = 0; r < 4; ++r) {
        const int t = wv * 32 + h * 16 + lk * 4 + r;   // D row = lk*4 + r
        s_part[pb + t] = bs[h][r];
        i_part[pb + t] = bi[h][r];
      }
    }
  }
}

// ---------------------------------------------------------------------------
// Combine + gather: 1024 blocks x 64 tokens. Pick min over the 2 halves,
// loss partial = sum(znorm + s_win), stream z_q rows to out (float4).
// ---------------------------------------------------------------------------
__global__ __launch_bounds__(256) void vq_gather(
    const float* __restrict__ emb, const float* __restrict__ s_part,
    const int* __restrict__ i_part, const float* __restrict__ znorm,
    float* __restrict__ out, float* __restrict__ part2) {
  __shared__ int idx_lds[64];
  const int tid = threadIdx.x;
  const int lane = tid & 63;
  const int wv = tid >> 6;
  const int blk = blockIdx.x;

  if (tid < 64) {     // wave 0 combines + reduces loss
    const int tok = blk * 64 + tid;
    const float s0 = s_part[tok];
    const float s1 = s_part[N_TOKS + tok];
    const int ii = (s1 < s0) ? i_part[N_TOKS + tok] : i_part[tok];
    idx_lds[tid] = ii;
    float l = znorm[tok] + fminf(s0, s1);
    #pragma unroll
    for (int m = 1; m < 64; m <<= 1) l += __shfl_xor(l, m);
    if (tid == 0) part2[blk] = l;
  }
  __syncthreads();

  const float4* emb4 = (const float4*)emb;
  float4*       out4 = (float4*)out;
  #pragma unroll 4
  for (int t2 = 0; t2 < 16; ++t2) {
    const int token = wv * 16 + t2;
    const int ci = idx_lds[token];
    out4[((size_t)blk * 64 + token) * 64 + lane] = emb4[(size_t)ci * 64 + lane];
  }
}

// ---------------------------------------------------------------------------
// Final deterministic loss reduction: 1024 partials -> scalar
// ---------------------------------------------------------------------------
__global__ __launch_bounds__(256) void vq_loss(const float* __restrict__ partials,
                                               float* __restrict__ lossOut) {
  const int tid = threadIdx.x;
  float v = partials[tid] + partials[tid + 256] + partials[tid + 512] + partials[tid + 768];
  #pragma unroll
  for (int m = 1; m < 64; m <<= 1) v += __shfl_xor(v, m);
  __shared__ float ws2[4];
  if ((tid & 63) == 0) ws2[tid >> 6] = v;
  __syncthreads();
  if (tid == 0)
    lossOut[0] = (ws2[0] + ws2[1] + ws2[2] + ws2[3]) * (1.25f / 16777216.f);
}

extern "C" void kernel_launch(void* const* d_in, const int* in_sizes, int n_in,
                              void* d_out, int out_size, void* d_ws, size_t ws_size,
                              hipStream_t stream) {
  const float* z   = (const float*)d_in[0];   // 65536 x 256 fp32
  const float* emb = (const float*)d_in[1];   // 1024 x 256 fp32
  float* out = (float*)d_out;                 // 16777216 + 1 fp32

  char* ws = (char*)d_ws;
  ushort_t* embT  = (ushort_t*)ws;                         // 512 KB
  float*    enorm = (float*)(ws + (512 << 10));            // 4 KB
  float*    s_prt = (float*)(ws + (516 << 10));            // 512 KB
  int*      i_prt = (int*)  (ws + (1028 << 10));           // 512 KB
  float*    znrm  = (float*)(ws + (1540 << 10));           // 256 KB
  float*    part2 = (float*)(ws + (1796 << 10));           // 4 KB

  vq_prep<<<N_E, 256, 0, stream>>>(emb, embT, enorm);
  vq_main<<<1024, 256, 0, stream>>>(z, embT, enorm, s_prt, i_prt, znrm);
  vq_gather<<<1024, 256, 0, stream>>>(emb, s_prt, i_prt, znrm, out, part2);
  vq_loss<<<1, 256, 0, stream>>>(part2, out + (size_t)N_TOKS * E_DIM);
}

// Round 4
// 91.460 us; speedup vs baseline: 1.1313x; 1.1313x over previous
//
#include <hip/hip_runtime.h>
#include <hip/hip_bf16.h>
#include <float.h>

typedef __attribute__((ext_vector_type(8))) short short8;
typedef __attribute__((ext_vector_type(4))) float f32x4;
typedef unsigned short ushort_t;

#define N_E   1024
#define E_DIM 256
#define N_TOKS 65536

// round-to-nearest-even fp32 -> bf16
__device__ inline ushort_t f2bf(float f) {
  unsigned int u = __float_as_uint(f);
  unsigned int r = u + 0x7FFFu + ((u >> 16) & 1u);
  return (ushort_t)(r >> 16);
}

// ---------------------------------------------------------------------------
// Prep: emb fp32 -> bf16 in MFMA-B-fragment order + enorm = sum(e^2)
// byte = (code/16)*8192 + (k/8)*256 + (code%16)*16 + (k%8)*2
// ---------------------------------------------------------------------------
__global__ __launch_bounds__(256) void vq_prep(const float* __restrict__ emb,
                                               ushort_t* __restrict__ embT,
                                               float* __restrict__ enorm) {
  const int code = blockIdx.x;     // 0..1023
  const int t    = threadIdx.x;    // 0..255 = k
  float v = emb[(size_t)code * E_DIM + t];
  embT[(size_t)(code >> 4) * 4096 + (t >> 3) * 128 + (code & 15) * 8 + (t & 7)] = f2bf(v);
  float sq = v * v;
  #pragma unroll
  for (int m = 1; m < 64; m <<= 1) sq += __shfl_xor(sq, m);
  __shared__ float ws3[4];
  if ((t & 63) == 0) ws3[t >> 6] = sq;
  __syncthreads();
  if (t == 0) enorm[code] = ws3[0] + ws3[1] + ws3[2] + ws3[3];
}

// ---------------------------------------------------------------------------
// Main: 1024 blocks x 1 wave (64 threads). Each wave owns 64 tokens:
// A-frags for 4 token-groups of 16 held in registers (128 VGPR).
// Codebook streamed as 64 tiles of 16 codes (8 KB) through wave-PRIVATE
// triple-buffered LDS via global_load_lds; ZERO barriers — pacing by counted
// s_waitcnt vmcnt only (same-wave DMA->ds_read is program-ordered).
// Per tile: 8 ds_read_b128 -> 32 MFMA (B-frag reused 4x).
// Epilogue fused: argmin reduce, gather emb rows -> out, loss partial.
// ---------------------------------------------------------------------------
__global__ __launch_bounds__(64) void vq_main(
    const float* __restrict__ z, const ushort_t* __restrict__ embT,
    const float* __restrict__ enorm, const float* __restrict__ emb,
    float* __restrict__ out, float* __restrict__ partials) {
  __shared__ ushort_t ldsB[3][4096];   // 3 x 8 KB, wave-private (1 wave/block)
  __shared__ float enorm_lds[N_E];     // 4 KB
  __shared__ float znorm_lds[64];
  __shared__ float s_lds[64];
  __shared__ int   idx_lds[64];

  const int lane = threadIdx.x;        // 0..63
  const int blk  = blockIdx.x;         // 0..1023
  const int lrow = lane & 15;          // A: token row; B/D: code col
  const int lk   = lane >> 4;          // k-group / D row-group

  const char* gbase = (const char*)embT;
  // tile = 16 codes x 256 k = 8 KB; this wave stages all of it (8 x 1 KB)
#define STAGE(BUF, TILE) do {                                                  \
    const char* g_ = gbase + (size_t)(TILE) * 8192 + lane * 16;                \
    char* lp_ = (char*)&ldsB[(BUF)][0];                                        \
    _Pragma("unroll")                                                          \
    for (int i_ = 0; i_ < 8; ++i_)                                             \
      __builtin_amdgcn_global_load_lds(                                        \
          (const __attribute__((address_space(1))) void*)(g_ + i_ * 1024),     \
          (__attribute__((address_space(3))) void*)(lp_ + i_ * 1024), 16, 0, 0);\
  } while (0)

  // prefetch tiles 0,1 — latency hides under the z-load/convert phase
  STAGE(0, 0);
  STAGE(1, 1);

  // ---- A fragments (z -> bf16) + fp32 znorm, 4 groups = 64 tokens ----------
  short8 afr[4][8];
  #pragma unroll
  for (int g = 0; g < 4; ++g) {
    const float* zp = z + (size_t)(blk * 64 + g * 16 + lrow) * E_DIM + lk * 8;
    float zn = 0.f;
    #pragma unroll
    for (int kk = 0; kk < 8; ++kk) {
      float4 v0 = *(const float4*)(zp + kk * 32);
      float4 v1 = *(const float4*)(zp + kk * 32 + 4);
      zn += v0.x * v0.x + v0.y * v0.y + v0.z * v0.z + v0.w * v0.w;
      zn += v1.x * v1.x + v1.y * v1.y + v1.z * v1.z + v1.w * v1.w;
      short8 a;
      a[0] = (short)f2bf(v0.x); a[1] = (short)f2bf(v0.y);
      a[2] = (short)f2bf(v0.z); a[3] = (short)f2bf(v0.w);
      a[4] = (short)f2bf(v1.x); a[5] = (short)f2bf(v1.y);
      a[6] = (short)f2bf(v1.z); a[7] = (short)f2bf(v1.w);
      afr[g][kk] = a;
    }
    zn += __shfl_xor(zn, 16);
    zn += __shfl_xor(zn, 32);
    if (lk == 0) znorm_lds[g * 16 + lrow] = zn;
  }

  // enorm -> LDS (1024 floats, 16 per lane)
  #pragma unroll
  for (int i = 0; i < 4; ++i)
    ((float4*)enorm_lds)[lane + i * 64] = ((const float4*)enorm)[lane + i * 64];

  float bs[4][4];
  int   bi[4][4];
  #pragma unroll
  for (int g = 0; g < 4; ++g)
    #pragma unroll
    for (int r = 0; r < 4; ++r) { bs[g][r] = FLT_MAX; bi[g][r] = 0; }

  int cb = 0;   // compute buffer
  int sb = 2;   // stage buffer
  for (int t = 0; t < 64; ++t) {
    // stage tile t+2, then ensure tile t landed: outstanding <= 16 means
    // only tiles t+1,t+2 (8 loads each) can still be in flight.
    if (t < 62) {
      STAGE(sb, t + 2);
      asm volatile("s_waitcnt vmcnt(16)" ::: "memory");
    } else if (t == 62) {
      asm volatile("s_waitcnt vmcnt(8)" ::: "memory");
    } else {
      asm volatile("s_waitcnt vmcnt(0)" ::: "memory");
    }
    const char* tb = (const char*)&ldsB[cb][0] + lk * 256 + lrow * 16;
    f32x4 acc[4];
    #pragma unroll
    for (int g = 0; g < 4; ++g) acc[g] = (f32x4){0.f, 0.f, 0.f, 0.f};
    #pragma unroll
    for (int kk = 0; kk < 8; ++kk) {
      short8 bfr = *(const short8*)(tb + kk * 1024);
      #pragma unroll
      for (int g = 0; g < 4; ++g)
        acc[g] = __builtin_amdgcn_mfma_f32_16x16x32_bf16(afr[g][kk], bfr, acc[g], 0, 0, 0);
    }
    const float en  = enorm_lds[t * 16 + lrow];
    const int  code = t * 16 + lrow;
    #pragma unroll
    for (int g = 0; g < 4; ++g)
      #pragma unroll
      for (int r = 0; r < 4; ++r) {
        float s = fmaf(-2.f, acc[g][r], en);
        if (s < bs[g][r]) { bs[g][r] = s; bi[g][r] = code; }
      }
    cb = cb + 1; if (cb >= 3) cb = 0;
    sb = sb + 1; if (sb >= 3) sb = 0;
  }
#undef STAGE

  // ---- cross-lane argmin reduce over the 16 code columns -------------------
  #pragma unroll
  for (int m = 1; m < 16; m <<= 1) {
    #pragma unroll
    for (int g = 0; g < 4; ++g)
      #pragma unroll
      for (int r = 0; r < 4; ++r) {
        float s2 = __shfl_xor(bs[g][r], m);
        int   i2 = __shfl_xor(bi[g][r], m);
        if (s2 < bs[g][r] || (s2 == bs[g][r] && i2 < bi[g][r])) {
          bs[g][r] = s2; bi[g][r] = i2;
        }
      }
  }
  if (lrow == 0) {
    #pragma unroll
    for (int g = 0; g < 4; ++g)
      #pragma unroll
      for (int r = 0; r < 4; ++r) {
        const int tl = g * 16 + lk * 4 + r;   // D row = lk*4 + r
        s_lds[tl]   = bs[g][r];
        idx_lds[tl] = bi[g][r];
      }
  }
  // same-wave LDS write->read: ordered by lgkmcnt, no barrier needed

  // ---- epilogue: gather z_q rows (1 KB coalesced per token) ----------------
  const float4* emb4 = (const float4*)emb;
  float4*       out4 = (float4*)out;
  const size_t outBase = (size_t)blk * 64;
  #pragma unroll 8
  for (int t2 = 0; t2 < 64; ++t2) {
    const int ci = idx_lds[t2];
    out4[(outBase + t2) * 64 + lane] = emb4[(size_t)ci * 64 + lane];
  }

  // ---- loss partial: sum over 64 tokens of (znorm + s_best) ----------------
  float lt = znorm_lds[lane] + s_lds[lane];
  #pragma unroll
  for (int m = 1; m < 64; m <<= 1) lt += __shfl_xor(lt, m);
  if (lane == 0) partials[blk] = lt;
}

// ---------------------------------------------------------------------------
// Final deterministic loss reduction: 1024 partials -> scalar
// ---------------------------------------------------------------------------
__global__ __launch_bounds__(256) void vq_loss(const float* __restrict__ partials,
                                               float* __restrict__ lossOut) {
  const int tid = threadIdx.x;
  float v = partials[tid] + partials[tid + 256] + partials[tid + 512] + partials[tid + 768];
  #pragma unroll
  for (int m = 1; m < 64; m <<= 1) v += __shfl_xor(v, m);
  __shared__ float ws2[4];
  if ((tid & 63) == 0) ws2[tid >> 6] = v;
  __syncthreads();
  if (tid == 0)
    lossOut[0] = (ws2[0] + ws2[1] + ws2[2] + ws2[3]) * (1.25f / 16777216.f);
}

extern "C" void kernel_launch(void* const* d_in, const int* in_sizes, int n_in,
                              void* d_out, int out_size, void* d_ws, size_t ws_size,
                              hipStream_t stream) {
  const float* z   = (const float*)d_in[0];   // 65536 x 256 fp32
  const float* emb = (const float*)d_in[1];   // 1024 x 256 fp32
  float* out = (float*)d_out;                 // 16777216 + 1 fp32

  char* ws = (char*)d_ws;
  ushort_t* embT  = (ushort_t*)ws;                   // 512 KB
  float*    enorm = (float*)(ws + (512 << 10));      // 4 KB
  float*    parts = (float*)(ws + (516 << 10));      // 4 KB

  vq_prep<<<N_E, 256, 0, stream>>>(emb, embT, enorm);
  vq_main<<<N_TOKS / 64, 64, 0, stream>>>(z, embT, enorm, emb, out, parts);
  vq_loss<<<1, 256, 0, stream>>>(parts, out + (size_t)N_TOKS * E_DIM);
}

// Round 5
// 68.195 us; speedup vs baseline: 1.5172x; 1.3412x over previous
//
#include <hip/hip_runtime.h>
#include <hip/hip_bf16.h>
#include <float.h>

typedef __attribute__((ext_vector_type(8))) short short8;
typedef __attribute__((ext_vector_type(4))) float f32x4;
typedef unsigned short ushort_t;

#define N_E   1024
#define E_DIM 256
#define N_TOKS 65536

// round-to-nearest-even fp32 -> bf16
__device__ inline ushort_t f2bf(float f) {
  unsigned int u = __float_as_uint(f);
  unsigned int r = u + 0x7FFFu + ((u >> 16) & 1u);
  return (ushort_t)(r >> 16);
}

// ---------------------------------------------------------------------------
// Prep: emb fp32 -> bf16 in MFMA-B-fragment order + enorm = sum(e^2)
// byte = (code/16)*8192 + (k/8)*256 + (code%16)*16 + (k%8)*2
// ---------------------------------------------------------------------------
__global__ __launch_bounds__(256) void vq_prep(const float* __restrict__ emb,
                                               ushort_t* __restrict__ embT,
                                               float* __restrict__ enorm) {
  const int code = blockIdx.x;     // 0..1023
  const int t    = threadIdx.x;    // 0..255 = k
  float v = emb[(size_t)code * E_DIM + t];
  embT[(size_t)(code >> 4) * 4096 + (t >> 3) * 128 + (code & 15) * 8 + (t & 7)] = f2bf(v);
  float sq = v * v;
  #pragma unroll
  for (int m = 1; m < 64; m <<= 1) sq += __shfl_xor(sq, m);
  __shared__ float ws3[4];
  if ((t & 63) == 0) ws3[t >> 6] = sq;
  __syncthreads();
  if (t == 0) enorm[code] = ws3[0] + ws3[1] + ws3[2] + ws3[3];
}

// ---------------------------------------------------------------------------
// Main: 512 blocks x 4 waves, 128 tokens/block (32/wave). Codebook streamed
// as 64 tiles of 16 codes (8 KB) through 4 shared LDS buffers,
// 3-tiles-ahead prefetch, counted vmcnt(6) + raw s_barrier per tile.
// Tile order ROTATED per block ((blk*11)&63) to decorrelate L2 bank traffic
// across the 512 resident blocks. setprio(1) around the MFMA cluster.
// ---------------------------------------------------------------------------
__global__ __launch_bounds__(256, 2) void vq_main(
    const float* __restrict__ z, const ushort_t* __restrict__ embT,
    const float* __restrict__ enorm, const float* __restrict__ emb,
    float* __restrict__ out, float* __restrict__ partials) {
  __shared__ ushort_t ldsB[4][4096];   // 4 x 8 KB tile buffers
  __shared__ float enorm_lds[N_E];     // 4 KB
  __shared__ float znorm_lds[128];
  __shared__ float s_lds[128];
  __shared__ int   idx_lds[128];
  __shared__ float wsum[4];

  const int tid  = threadIdx.x;
  const int lane = tid & 63;
  const int wv   = tid >> 6;
  const int blk  = blockIdx.x;
  const int lrow = lane & 15;   // A: token row; B/D: code col
  const int lk   = lane >> 4;   // k-group / D row-group
  const int start = (blk * 11) & 63;   // rotated tile-walk start

  const char* gbase = (const char*)embT;
  // tile = 16 codes x 256 k = 8 KB; each wave stages its 2 KB quarter
#define STAGE(BUF, TILE) do {                                                  \
    const char* g_ = gbase + (size_t)(TILE) * 8192 + wv * 2048 + lane * 16;    \
    char* lp_ = ((char*)&ldsB[(BUF)][0]) + wv * 2048;                          \
    __builtin_amdgcn_global_load_lds(                                          \
        (const __attribute__((address_space(1))) void*)g_,                     \
        (__attribute__((address_space(3))) void*)lp_, 16, 0, 0);               \
    __builtin_amdgcn_global_load_lds(                                          \
        (const __attribute__((address_space(1))) void*)(g_ + 1024),            \
        (__attribute__((address_space(3))) void*)(lp_ + 1024), 16, 0, 0);      \
  } while (0)

  // prologue: prefetch tiles start..start+2 (land during z-load phase)
  STAGE(0, start);
  STAGE(1, (start + 1) & 63);
  STAGE(2, (start + 2) & 63);

  // ---- A fragments (z -> bf16) + fp32 znorm --------------------------------
  short8 afr[2][8];
  #pragma unroll
  for (int h = 0; h < 2; ++h) {
    const float* zp = z + (size_t)(blk * 128 + wv * 32 + h * 16 + lrow) * E_DIM + lk * 8;
    float zn = 0.f;
    #pragma unroll
    for (int kk = 0; kk < 8; ++kk) {
      float4 v0 = *(const float4*)(zp + kk * 32);
      float4 v1 = *(const float4*)(zp + kk * 32 + 4);
      zn += v0.x * v0.x + v0.y * v0.y + v0.z * v0.z + v0.w * v0.w;
      zn += v1.x * v1.x + v1.y * v1.y + v1.z * v1.z + v1.w * v1.w;
      short8 a;
      a[0] = (short)f2bf(v0.x); a[1] = (short)f2bf(v0.y);
      a[2] = (short)f2bf(v0.z); a[3] = (short)f2bf(v0.w);
      a[4] = (short)f2bf(v1.x); a[5] = (short)f2bf(v1.y);
      a[6] = (short)f2bf(v1.z); a[7] = (short)f2bf(v1.w);
      afr[h][kk] = a;
    }
    zn += __shfl_xor(zn, 16);
    zn += __shfl_xor(zn, 32);
    if (lane < 16) znorm_lds[wv * 32 + h * 16 + lane] = zn;
  }

  // enorm -> LDS (1024 floats)
  ((float4*)enorm_lds)[tid] = ((const float4*)enorm)[tid];

  __syncthreads();   // drains prologue DMA (vmcnt 0) + LDS writes

  float bs[2][4];
  int   bi[2][4];
  #pragma unroll
  for (int r = 0; r < 4; ++r) {
    bs[0][r] = FLT_MAX; bs[1][r] = FLT_MAX; bi[0][r] = 0; bi[1][r] = 0;
  }

  for (int t = 0; t < 64; ++t) {
    const int rt = (t + start) & 63;          // rotated tile index
    if (t < 61) {
      STAGE((t + 3) & 3, (rt + 3) & 63);
      asm volatile("s_waitcnt vmcnt(6)" ::: "memory");   // tile t landed
    } else if (t == 61) {
      asm volatile("s_waitcnt vmcnt(4)" ::: "memory");
    } else if (t == 62) {
      asm volatile("s_waitcnt vmcnt(2)" ::: "memory");
    } else {
      asm volatile("s_waitcnt vmcnt(0)" ::: "memory");
    }
    __builtin_amdgcn_s_barrier();             // all waves' quarters landed

    const char* tb = (const char*)&ldsB[t & 3][0] + lk * 256 + lrow * 16;
    f32x4 acc0 = {0.f, 0.f, 0.f, 0.f};
    f32x4 acc1 = {0.f, 0.f, 0.f, 0.f};
    __builtin_amdgcn_s_setprio(1);
    #pragma unroll
    for (int kk = 0; kk < 8; ++kk) {
      short8 bfr = *(const short8*)(tb + kk * 1024);
      acc0 = __builtin_amdgcn_mfma_f32_16x16x32_bf16(afr[0][kk], bfr, acc0, 0, 0, 0);
      acc1 = __builtin_amdgcn_mfma_f32_16x16x32_bf16(afr[1][kk], bfr, acc1, 0, 0, 0);
    }
    __builtin_amdgcn_s_setprio(0);
    const float en  = enorm_lds[rt * 16 + lrow];
    const int  code = rt * 16 + lrow;
    #pragma unroll
    for (int r = 0; r < 4; ++r) {
      float s0 = fmaf(-2.f, acc0[r], en);
      if (s0 < bs[0][r]) { bs[0][r] = s0; bi[0][r] = code; }
      float s1 = fmaf(-2.f, acc1[r], en);
      if (s1 < bs[1][r]) { bs[1][r] = s1; bi[1][r] = code; }
    }
  }
#undef STAGE

  // ---- cross-lane argmin reduce over the 16 code columns -------------------
  #pragma unroll
  for (int m = 1; m < 16; m <<= 1) {
    #pragma unroll
    for (int h = 0; h < 2; ++h) {
      #pragma unroll
      for (int r = 0; r < 4; ++r) {
        float s2 = __shfl_xor(bs[h][r], m);
        int   i2 = __shfl_xor(bi[h][r], m);
        if (s2 < bs[h][r] || (s2 == bs[h][r] && i2 < bi[h][r])) {
          bs[h][r] = s2; bi[h][r] = i2;
        }
      }
    }
  }
  if (lrow == 0) {
    #pragma unroll
    for (int h = 0; h < 2; ++h) {
      #pragma unroll
      for (int r = 0; r < 4; ++r) {
        const int tl = wv * 32 + h * 16 + lk * 4 + r;   // D row = lk*4 + r
        s_lds[tl]   = bs[h][r];
        idx_lds[tl] = bi[h][r];
      }
    }
  }
  __syncthreads();

  // ---- epilogue: each wave gathers its own 32 tokens (float4/lane) ---------
  const float4* emb4 = (const float4*)emb;
  float4*       out4 = (float4*)out;
  const size_t outBase = (size_t)blk * 128;
  #pragma unroll 4
  for (int t2 = 0; t2 < 32; ++t2) {
    const int token = wv * 32 + t2;
    const int ci = idx_lds[token];
    out4[(outBase + token) * 64 + lane] = emb4[(size_t)ci * 64 + lane];
  }

  // ---- loss: sum_t (znorm_t + s_best_t) ------------------------------------
  float lt = 0.f;
  if (tid < 128) lt = znorm_lds[tid] + s_lds[tid];
  #pragma unroll
  for (int m = 1; m < 64; m <<= 1) lt += __shfl_xor(lt, m);
  if (lane == 0) wsum[wv] = lt;
  __syncthreads();
  if (tid == 0) partials[blk] = wsum[0] + wsum[1] + wsum[2] + wsum[3];
}

// ---------------------------------------------------------------------------
// Final deterministic loss reduction: 512 partials -> scalar
// ---------------------------------------------------------------------------
__global__ __launch_bounds__(256) void vq_loss(const float* __restrict__ partials,
                                               float* __restrict__ lossOut) {
  const int tid = threadIdx.x;
  float v = partials[tid] + partials[tid + 256];
  #pragma unroll
  for (int m = 1; m < 64; m <<= 1) v += __shfl_xor(v, m);
  __shared__ float ws2[4];
  if ((tid & 63) == 0) ws2[tid >> 6] = v;
  __syncthreads();
  if (tid == 0)
    lossOut[0] = (ws2[0] + ws2[1] + ws2[2] + ws2[3]) * (1.25f / 16777216.f);
}

extern "C" void kernel_launch(void* const* d_in, const int* in_sizes, int n_in,
                              void* d_out, int out_size, void* d_ws, size_t ws_size,
                              hipStream_t stream) {
  const float* z   = (const float*)d_in[0];   // 65536 x 256 fp32
  const float* emb = (const float*)d_in[1];   // 1024 x 256 fp32
  float* out = (float*)d_out;                 // 16777216 + 1 fp32

  char* ws = (char*)d_ws;
  ushort_t* embT  = (ushort_t*)ws;                   // 512 KB
  float*    enorm = (float*)(ws + (512 << 10));      // 4 KB
  float*    parts = (float*)(ws + (516 << 10));      // 4 KB

  vq_prep<<<N_E, 256, 0, stream>>>(emb, embT, enorm);
  vq_main<<<N_TOKS / 128, 256, 0, stream>>>(z, embT, enorm, emb, out, parts);
  vq_loss<<<1, 256, 0, stream>>>(parts, out + (size_t)N_TOKS * E_DIM);
}